// Round 5
// baseline (828.750 us; speedup 1.0000x reference)
//
#include <hip/hip_runtime.h>
#include <cmath>

typedef unsigned short u16;
typedef unsigned int   u32;
typedef __attribute__((ext_vector_type(8))) short bf16x8;
typedef __attribute__((ext_vector_type(4))) float f32x4;
typedef __attribute__((ext_vector_type(4))) u32   u32x4;

__device__ __forceinline__ float bf2f(u16 u){
    union { u32 i; float f; } x; x.i = ((u32)u) << 16; return x.f;
}
__device__ __forceinline__ u16 f2bf(float f){
    union { float f; u32 i; } x; x.f = f;
    u32 r = x.i + 0x7fffu + ((x.i >> 16) & 1u);
    return (u16)(r >> 16);
}

// ---------------- graph preprocessing ----------------

__global__ void k_count(const int* __restrict__ src, const int* __restrict__ dst,
                        int* cnt, int* notsink, int* pos, int E){
    int e = blockIdx.x*256 + threadIdx.x;
    if (e < E){
        pos[e] = atomicAdd(&cnt[dst[e]], 1);
        notsink[src[e]] = 1;   // benign race: all writers store 1
    }
}

__global__ void k_scan1(const int* __restrict__ in, int* blocksum, int N){
    __shared__ int sh[256];
    int tid = threadIdx.x;
    int base = blockIdx.x*1024 + tid*4;
    int s = 0;
    for (int j=0;j<4;j++){ int i = base+j; s += (i < N) ? in[i] : 0; }
    sh[tid] = s; __syncthreads();
    for (int d=128; d>0; d>>=1){ if (tid < d) sh[tid] += sh[tid+d]; __syncthreads(); }
    if (tid == 0) blocksum[blockIdx.x] = sh[0];
}

__global__ void k_scan2(int* blocksum, int nb){
    if (threadIdx.x == 0){
        int run = 0;
        for (int i=0;i<nb;i++){ int v = blocksum[i]; blocksum[i] = run; run += v; }
    }
}

__global__ void k_scan3(const int* __restrict__ in, const int* __restrict__ blockoff,
                        int* out, float* inv_deg, float* haspred, int N){
    __shared__ int sh[256];
    int tid = threadIdx.x;
    int base = blockIdx.x*1024 + tid*4;
    int e[4]; int s = 0;
    for (int j=0;j<4;j++){ int i = base+j; e[j] = (i < N) ? in[i] : 0; s += e[j]; }
    sh[tid] = s; __syncthreads();
    for (int d=1; d<256; d<<=1){
        int t = (tid >= d) ? sh[tid-d] : 0;
        __syncthreads();
        sh[tid] += t;
        __syncthreads();
    }
    int excl = sh[tid] - s + blockoff[blockIdx.x];
    for (int j=0;j<4;j++){
        int i = base+j;
        if (i < N){
            out[i] = excl; excl += e[j];
            inv_deg[i] = 1.0f / (float)(e[j] > 1 ? e[j] : 1);
            haspred[i] = e[j] > 0 ? 1.0f : 0.0f;
        }
    }
}

__global__ void k_place(const int* __restrict__ src, const int* __restrict__ dst,
                        const int* __restrict__ row_ptr, const int* __restrict__ pos,
                        int* csr_src, int E){
    int e = blockIdx.x*256 + threadIdx.x;
    if (e < E)
        csr_src[row_ptr[dst[e]] + pos[e]] = src[e];
}

// transpose+convert weight matrices: f32 [K][128] -> bf16 [128][K]; shift = log2(K*128)
__global__ void k_wt(const float* __restrict__ in, u16* __restrict__ out,
                     int shift, int K, int total){
    int i = blockIdx.x*256 + threadIdx.x;
    if (i < total){
        int mat = i >> shift;
        int within = i & ((1 << shift) - 1);
        int k = within >> 7, n = within & 127;
        out[(size_t)mat*(K*128) + n*K + k] = f2bf(in[i]);
    }
}

// ---------------- shared GEMM tile machinery ----------------

__device__ __forceinline__ void stage_A_bf16(const u16* __restrict__ A, u16 (*lA)[136],
                                             int row0, int n_rows, int tid){
    #pragma unroll
    for (int i=0;i<4;i++){
        int c = i*256 + tid;
        int r = c >> 4, col8 = (c & 15) * 8;
        u32x4 v = {0,0,0,0};
        if (row0 + r < n_rows)
            v = *(const u32x4*)(A + (size_t)(row0 + r)*128 + col8);
        *(u32x4*)&lA[r][col8] = v;
    }
}

__device__ __forceinline__ void stage_A_f32(const float* __restrict__ A, u16 (*lA)[136],
                                            int row0, int n_rows, int tid){
    #pragma unroll
    for (int i=0;i<4;i++){
        int c = i*256 + tid;
        int r = c >> 4, col8 = (c & 15) * 8;
        u16 o[8] = {0,0,0,0,0,0,0,0};
        if (row0 + r < n_rows){
            float4 v0 = *(const float4*)(A + (size_t)(row0 + r)*128 + col8);
            float4 v1 = *(const float4*)(A + (size_t)(row0 + r)*128 + col8 + 4);
            o[0]=f2bf(v0.x); o[1]=f2bf(v0.y); o[2]=f2bf(v0.z); o[3]=f2bf(v0.w);
            o[4]=f2bf(v1.x); o[5]=f2bf(v1.y); o[6]=f2bf(v1.z); o[7]=f2bf(v1.w);
        }
        *(u32x4*)&lA[r][col8] = *(const u32x4*)o;
    }
}

// full-K B stage: 128 cols x 128 k
__device__ __forceinline__ void stage_B(const u16* __restrict__ BT, int Ks, int koff0,
                                        u16 (*lB)[136], int tid){
    #pragma unroll
    for (int i=0;i<8;i++){
        int c = i*256 + tid;
        int n = c >> 4, col8 = (c & 15) * 8;
        u32x4 v = *(const u32x4*)(BT + (size_t)n*Ks + koff0 + col8);
        *(u32x4*)&lB[n][col8] = v;
    }
}

// half-K B stage: 128 cols x 64 k window starting at koff0
__device__ __forceinline__ void stage_B_half(const u16* __restrict__ BT, int Ks, int koff0,
                                             u16 (*lB)[72], int tid){
    #pragma unroll
    for (int i=0;i<4;i++){
        int c = i*256 + tid;
        int n = c >> 3, col8 = (c & 7) * 8;
        *(u32x4*)&lB[n][col8] = *(const u32x4*)(BT + (size_t)n*Ks + koff0 + col8);
    }
}

__device__ __forceinline__ void mfma_tile(const u16 (*lA)[136], const u16 (*lB)[136],
                                          int wave, int lane, f32x4* acc){
    #pragma unroll
    for (int kk=0;kk<4;kk++){
        int koff = kk*32 + (lane >> 4) * 8;
        bf16x8 a = *(const bf16x8*)&lA[wave*16 + (lane & 15)][koff];
        #pragma unroll
        for (int t=0;t<8;t++){
            bf16x8 b = *(const bf16x8*)&lB[t*16 + (lane & 15)][koff];
            acc[t] = __builtin_amdgcn_mfma_f32_16x16x32_bf16(a, b, acc[t], 0, 0, 0);
        }
    }
}

__device__ __forceinline__ void mfma_half(const u16 (*lA)[136], const u16 (*lB)[72],
                                          int wave, int lane, int kbaseA, f32x4* acc){
    #pragma unroll
    for (int kk=0;kk<2;kk++){
        int kw = kk*32 + (lane >> 4) * 8;
        bf16x8 a = *(const bf16x8*)&lA[wave*16 + (lane & 15)][kbaseA + kw];
        #pragma unroll
        for (int t=0;t<8;t++){
            bf16x8 b = *(const bf16x8*)&lB[t*16 + (lane & 15)][kw];
            acc[t] = __builtin_amdgcn_mfma_f32_16x16x32_bf16(a, b, acc[t], 0, 0, 0);
        }
    }
}

// ---------------- GEMM: h0 = f32 feats @ W_in + b_in -> bf16 ----------------

__global__ __launch_bounds__(256) void k_gemm_in(
    const float* __restrict__ A, const u16* __restrict__ BT,
    const float* __restrict__ bias, u16* __restrict__ C, int n_rows)
{
    __shared__ u16 lA[64][136];
    __shared__ u16 lB[128][136];
    int tid = threadIdx.x, wave = tid >> 6, lane = tid & 63;
    int row0 = blockIdx.x * 64;
    f32x4 acc[8];
    #pragma unroll
    for (int t=0;t<8;t++) acc[t] = (f32x4){0.f,0.f,0.f,0.f};
    stage_A_f32(A, lA, row0, n_rows, tid);
    stage_B(BT, 128, 0, lB, tid);
    __syncthreads();
    mfma_tile(lA, lB, wave, lane, acc);

    int sl = lane & 15;
    int rbase = wave*16 + (lane >> 4)*4;
    float bc[8];
    #pragma unroll
    for (int t=0;t<8;t++) bc[t] = bias[t*16 + sl];
    for (int r=0;r<4;r++){
        int row = row0 + rbase + r;
        if (row >= n_rows) continue;
        #pragma unroll
        for (int t=0;t<8;t++)
            C[(size_t)row*128 + t*16 + sl] = f2bf(acc[t][r] + bc[t]);
    }
}

// -------- fused layer: gather neigh-mean in-block; M = h@Ws+bs+hp*(ng@Wn+bn);
//          g = sigmoid([h,M]@Wg+bg); v = g*M+(1-g)*h; LayerNorm; ReLU --------

__global__ __launch_bounds__(256) void k_layer(
    const u16* __restrict__ H,
    const int* __restrict__ row_ptr, const int* __restrict__ indeg,
    const float* __restrict__ inv_deg, const int* __restrict__ csr_src,
    const u16* __restrict__ BsT, const u16* __restrict__ BnT,
    const u16* __restrict__ BgT,
    const float* __restrict__ bs, const float* __restrict__ bn,
    const float* __restrict__ bg,
    const float* __restrict__ gamma, const float* __restrict__ beta,
    const float* __restrict__ haspred,
    u16* __restrict__ Hb, float* __restrict__ Hf, int n_rows)
{
    __shared__ u16 lA[64][136];   // H tile (persists whole kernel)
    __shared__ u16 lM[64][136];   // gathered neigh tile, then M tile
    __shared__ u16 lB[128][72];   // half-K weight window
    int tid = threadIdx.x, wave = tid >> 6, lane = tid & 63;
    int sl = lane & 15, g16 = lane >> 4;   // 16-lane group id within wave
    int row0 = blockIdx.x * 64;

    // own h tile -> lA
    stage_A_bf16(H, lA, row0, n_rows, tid);

    // gather predecessor mean -> lM (16 lanes per node, 16 nodes/pass, 4 passes)
    #pragma unroll
    for (int pass=0; pass<4; pass++){
        int r = pass*16 + wave*4 + g16;
        int node = row0 + r;
        if (node < n_rows){
            float acc[8] = {0.f,0.f,0.f,0.f,0.f,0.f,0.f,0.f};
            int deg = indeg[node], start = row_ptr[node];
            for (int e0 = 0; e0 < deg; e0 += 16){   // deg uniform within 16-lane group
                int idx = (e0 + sl < deg) ? csr_src[start + e0 + sl] : 0;
                int c = deg - e0;
                #pragma unroll
                for (int j = 0; j < 16; j++){
                    int sidx = __shfl(idx, (g16 << 4) | j);
                    if (j < c){
                        bf16x8 v = *(const bf16x8*)(H + (size_t)sidx*128 + sl*8);
                        #pragma unroll
                        for (int t=0;t<8;t++) acc[t] += bf2f((u16)v[t]);
                    }
                }
            }
            float iv = inv_deg[node];
            u16 o[8];
            #pragma unroll
            for (int t=0;t<8;t++) o[t] = f2bf(acc[t]*iv);
            *(u32x4*)&lM[r][sl*8] = *(const u32x4*)o;
        } else {
            u32x4 z = {0,0,0,0};
            *(u32x4*)&lM[r][sl*8] = z;
        }
    }

    f32x4 accs[8], accn[8];
    #pragma unroll
    for (int t=0;t<8;t++){ accs[t] = (f32x4){0.f,0.f,0.f,0.f}; accn[t] = (f32x4){0.f,0.f,0.f,0.f}; }

    // phase 1: h @ Ws
    stage_B_half(BsT, 128, 0, lB, tid);
    __syncthreads();
    mfma_half(lA, lB, wave, lane, 0, accs);
    __syncthreads();
    stage_B_half(BsT, 128, 64, lB, tid);
    __syncthreads();
    mfma_half(lA, lB, wave, lane, 64, accs);
    __syncthreads();

    // phase 2: ng @ Wn
    stage_B_half(BnT, 128, 0, lB, tid);
    __syncthreads();
    mfma_half(lM, lB, wave, lane, 0, accn);
    __syncthreads();
    stage_B_half(BnT, 128, 64, lB, tid);
    __syncthreads();
    mfma_half(lM, lB, wave, lane, 64, accn);
    __syncthreads();

    // build M in LDS (C-layout write)
    int rbase = wave*16 + g16*4;
    {
        float bsc[8], bnc[8];
        #pragma unroll
        for (int t=0;t<8;t++){ bsc[t] = bs[t*16 + sl]; bnc[t] = bn[t*16 + sl]; }
        #pragma unroll
        for (int r=0;r<4;r++){
            int row = row0 + rbase + r;
            float hp = (row < n_rows) ? haspred[row] : 0.f;
            #pragma unroll
            for (int t=0;t<8;t++){
                float m = accs[t][r] + bsc[t] + hp*(accn[t][r] + bnc[t]);
                lM[rbase + r][t*16 + sl] = f2bf(m);
            }
        }
    }
    __syncthreads();

    // phase 3: gate = h @ Wg_top + M @ Wg_bot  (reuse accs)
    #pragma unroll
    for (int t=0;t<8;t++) accs[t] = (f32x4){0.f,0.f,0.f,0.f};
    stage_B_half(BgT, 256, 0, lB, tid);
    __syncthreads();
    mfma_half(lA, lB, wave, lane, 0, accs);
    __syncthreads();
    stage_B_half(BgT, 256, 64, lB, tid);
    __syncthreads();
    mfma_half(lA, lB, wave, lane, 64, accs);
    __syncthreads();
    stage_B_half(BgT, 256, 128, lB, tid);
    __syncthreads();
    mfma_half(lM, lB, wave, lane, 0, accs);
    __syncthreads();
    stage_B_half(BgT, 256, 192, lB, tid);
    __syncthreads();
    mfma_half(lM, lB, wave, lane, 64, accs);
    __syncthreads();

    // epilogue: gate, blend, LayerNorm, ReLU
    float bgc[8], gam[8], bet[8];
    #pragma unroll
    for (int t=0;t<8;t++){
        int col = t*16 + sl;
        bgc[t] = bg[col]; gam[t] = gamma[col]; bet[t] = beta[col];
    }
    for (int r=0;r<4;r++){
        int row = row0 + rbase + r;
        if (row >= n_rows) continue;   // quad-uniform
        float v[8], s = 0.f;
        #pragma unroll
        for (int t=0;t<8;t++){
            int col = t*16 + sl;
            float x = accs[t][r] + bgc[t];
            float gg = 1.f/(1.f + expf(-x));
            float hv = bf2f(lA[rbase + r][col]);   // h from LDS
            float mv = bf2f(lM[rbase + r][col]);   // M from LDS
            v[t] = gg*mv + (1.f - gg)*hv;
            s += v[t];
        }
        s += __shfl_xor(s,1); s += __shfl_xor(s,2); s += __shfl_xor(s,4); s += __shfl_xor(s,8);
        float mu = s * (1.f/128.f);
        float q = 0.f;
        #pragma unroll
        for (int t=0;t<8;t++){ float d = v[t]-mu; q += d*d; }
        q += __shfl_xor(q,1); q += __shfl_xor(q,2); q += __shfl_xor(q,4); q += __shfl_xor(q,8);
        float rs = rsqrtf(q*(1.f/128.f) + 1e-5f);
        #pragma unroll
        for (int t=0;t<8;t++){
            size_t idx = (size_t)row*128 + t*16 + sl;
            float o = (v[t]-mu)*rs*gam[t] + bet[t];
            o = o > 0.f ? o : 0.f;
            if (Hb) Hb[idx] = f2bf(o);
            if (Hf) Hf[idx] = o;
        }
    }
}

// ------- GEMM: scores = sinkmask( tanh(h@W_att+b_att) @ W_score + b_score ) -------

__global__ __launch_bounds__(256) void k_gemm_att(
    const float* __restrict__ H, const u16* __restrict__ BT,
    const float* __restrict__ b_att, const float* __restrict__ Wsc,
    const float* __restrict__ bsc, const int* __restrict__ notsink,
    float* __restrict__ scores, int n_rows)
{
    __shared__ u16 lA[64][136];
    __shared__ u16 lB[128][136];
    int tid = threadIdx.x, wave = tid >> 6, lane = tid & 63;
    int row0 = blockIdx.x * 64;
    f32x4 acc[8];
    #pragma unroll
    for (int t=0;t<8;t++) acc[t] = (f32x4){0.f,0.f,0.f,0.f};
    stage_A_f32(H, lA, row0, n_rows, tid);
    stage_B(BT, 128, 0, lB, tid);
    __syncthreads();
    mfma_tile(lA, lB, wave, lane, acc);

    int sl = lane & 15;
    int rbase = wave*16 + (lane >> 4)*4;
    float bac[8], wc[8];
    #pragma unroll
    for (int t=0;t<8;t++){ bac[t] = b_att[t*16 + sl]; wc[t] = Wsc[t*16 + sl]; }
    float b0 = bsc[0];
    for (int r=0;r<4;r++){
        int row = row0 + rbase + r;
        if (row >= n_rows) continue;
        float p = 0.f;
        #pragma unroll
        for (int t=0;t<8;t++) p += tanhf(acc[t][r] + bac[t]) * wc[t];
        p += __shfl_xor(p,1); p += __shfl_xor(p,2); p += __shfl_xor(p,4); p += __shfl_xor(p,8);
        if (sl == 0)
            scores[row] = (notsink[row] == 0) ? (p + b0) : -INFINITY;
    }
}

// ---------------- softmax-pool over sinks (no max: |score| <= ~5) ----------------

__global__ void k_sum1(const float* __restrict__ scores, float* part, int N){
    __shared__ float sh[256];
    int tid = threadIdx.x;
    float s = 0.f;
    for (int i = blockIdx.x*256 + tid; i < N; i += 256*256) s += expf(scores[i]);
    sh[tid] = s; __syncthreads();
    for (int d=128; d>0; d>>=1){ if (tid < d) sh[tid] += sh[tid+d]; __syncthreads(); }
    if (tid == 0) part[blockIdx.x] = sh[0];
}

__global__ void k_sum2(const float* __restrict__ part, float* invsum){
    __shared__ float sh[256];
    int tid = threadIdx.x;
    sh[tid] = part[tid]; __syncthreads();
    for (int d=128; d>0; d>>=1){ if (tid < d) sh[tid] += sh[tid+d]; __syncthreads(); }
    if (tid == 0) invsum[0] = 1.f / sh[0];
}

__global__ void k_emb1(const float* __restrict__ h, const float* __restrict__ scores,
                       float* accum, int N){
    __shared__ float sh[256];
    int tid = threadIdx.x;
    int col = tid & 127, grp = tid >> 7;
    float acc = 0.f;
    for (int n = blockIdx.x*2 + grp; n < N; n += 512){
        float s = scores[n];
        if (s > -1e30f)
            acc += expf(s) * h[(size_t)n*128 + col];
    }
    sh[tid] = acc; __syncthreads();
    if (tid < 128) atomicAdd(&accum[col], sh[tid] + sh[tid+128]);
}

__global__ void k_emb2(const float* __restrict__ accum, const float* __restrict__ invsum,
                       float* __restrict__ out){
    int c = threadIdx.x;
    if (c < 128) out[c] = accum[c] * invsum[0];
}

// ---------------- host launch ----------------

extern "C" void kernel_launch(void* const* d_in, const int* in_sizes, int n_in,
                              void* d_out, int out_size, void* d_ws, size_t ws_size,
                              hipStream_t stream)
{
    const float* node_feats = (const float*)d_in[0];
    const int* src     = (const int*)d_in[1];
    const int* dst     = (const int*)d_in[2];
    const float* W_in    = (const float*)d_in[3];
    const float* b_in    = (const float*)d_in[4];
    const float* Ws      = (const float*)d_in[5];
    const float* bs      = (const float*)d_in[6];
    const float* Wn      = (const float*)d_in[7];
    const float* bn      = (const float*)d_in[8];
    const float* Wg      = (const float*)d_in[9];
    const float* bg      = (const float*)d_in[10];
    const float* gamma   = (const float*)d_in[11];
    const float* beta    = (const float*)d_in[12];
    const float* W_att   = (const float*)d_in[13];
    const float* b_att   = (const float*)d_in[14];
    const float* W_score = (const float*)d_in[15];
    const float* b_score = (const float*)d_in[16];

    const int N = in_sizes[0] / 128;
    const int E = in_sizes[1];

    char* w = (char*)d_ws;
    auto alloc = [&](size_t bytes)->char* {
        char* p = w; w += (bytes + 255) & ~(size_t)255; return p;
    };
    u16* WT_in  = (u16*)alloc(128*128*2);
    u16* WT_s   = (u16*)alloc(3*128*128*2);
    u16* WT_n   = (u16*)alloc(3*128*128*2);
    u16* WT_g   = (u16*)alloc(3*128*256*2);
    u16* WT_att = (u16*)alloc(128*128*2);
    // zeroed region: cnt, notsink, emb_accum (contiguous)
    int* cnt      = (int*)alloc((size_t)N*4);
    int* notsink  = (int*)alloc((size_t)N*4);
    float* emb_accum = (float*)alloc(128*4);
    size_t zero_bytes = (size_t)((char*)(emb_accum + 128) - (char*)cnt);
    int* pos      = (int*)alloc((size_t)E*4);
    int* row_ptr  = (int*)alloc((size_t)N*4);
    int* blocksum = (int*)alloc(1024*4);
    int* csr_src  = (int*)alloc((size_t)E*4);
    float* inv_deg = (float*)alloc((size_t)N*4);
    float* haspred = (float*)alloc((size_t)N*4);
    float* scores  = (float*)alloc((size_t)N*4);
    float* part    = (float*)alloc(256*4);
    float* invsum  = (float*)alloc(256);
    u16* buf0 = (u16*)alloc((size_t)N*128*2);   // h ping
    u16* buf1 = (u16*)alloc((size_t)N*128*2);   // h pong

    float* h_out   = (float*)d_out;
    float* emb_out = h_out + (size_t)N*128;

    hipMemsetAsync(cnt, 0, zero_bytes, stream);

    k_wt<<<(16384+255)/256, 256, 0, stream>>>(W_in,  WT_in,  14, 128, 16384);
    k_wt<<<(49152+255)/256, 256, 0, stream>>>(Ws,    WT_s,   14, 128, 49152);
    k_wt<<<(49152+255)/256, 256, 0, stream>>>(Wn,    WT_n,   14, 128, 49152);
    k_wt<<<(98304+255)/256, 256, 0, stream>>>(Wg,    WT_g,   15, 256, 98304);
    k_wt<<<(16384+255)/256, 256, 0, stream>>>(W_att, WT_att, 14, 128, 16384);

    k_count<<<(E+255)/256, 256, 0, stream>>>(src, dst, cnt, notsink, pos, E);

    int nb = (N + 1023) / 1024;
    k_scan1<<<nb, 256, 0, stream>>>(cnt, blocksum, N);
    k_scan2<<<1, 256, 0, stream>>>(blocksum, nb);
    k_scan3<<<nb, 256, 0, stream>>>(cnt, blocksum, row_ptr, inv_deg, haspred, N);
    k_place<<<(E+255)/256, 256, 0, stream>>>(src, dst, row_ptr, pos, csr_src, E);

    int gblk = (N + 63) / 64;

    k_gemm_in<<<gblk, 256, 0, stream>>>(node_feats, WT_in, b_in, buf0, N);

    u16* hin = buf0;
    for (int i=0;i<3;i++){
        u16* hb  = (i == 2) ? nullptr : ((hin == buf0) ? buf1 : buf0);
        float* hf = (i == 2) ? h_out : nullptr;
        k_layer<<<gblk, 256, 0, stream>>>(hin, row_ptr, cnt, inv_deg, csr_src,
                                          WT_s + i*16384, WT_n + i*16384, WT_g + i*32768,
                                          bs + i*128, bn + i*128, bg + i*128,
                                          gamma + i*128, beta + i*128, haspred,
                                          hb, hf, N);
        if (i < 2) hin = hb;
    }

    k_gemm_att<<<gblk, 256, 0, stream>>>(h_out, WT_att, b_att, W_score, b_score,
                                         notsink, scores, N);
    k_sum1<<<256, 256, 0, stream>>>(scores, part, N);
    k_sum2<<<1, 256, 0, stream>>>(part, invsum);
    k_emb1<<<256, 256, 0, stream>>>(h_out, scores, emb_accum, N);
    k_emb2<<<1, 128, 0, stream>>>(emb_accum, invsum, emb_out);

    (void)n_in; (void)out_size; (void)ws_size;
}